// Round 1
// 85.688 us; speedup vs baseline: 1.4254x; 1.4254x over previous
//
#include <hip/hip_runtime.h>
#include <hip/hip_bf16.h>

// Problem: B=4096, F=512, C=64, MC=100, TRI=2080, N_all = 64+2080 = 2144
// Pipeline:
//  cvt:    x, [w_mu;w_sigma] -> bf16
//  gemm:   c_all = x @ W^T + bias. NEW: 128x128 tile, BK=64, LDS-staged via
//          global_load_lds(16B) with XOR-swizzled source (linear LDS dest,
//          swizzled ds_read) -> ~2-way bank conflicts. 17x32 grid, bijective
//          XCD remap (544 = 8*68, 4 complete row-bands per XCD L2).
//          epilogue: cols<64 -> Mu f32; cols in [64,2144) -> Sg bf16 triangular
//          (softplus+1e-6 on diagonal). Accumulation order identical to prev.
//  sample: out = sigmoid(mu + L @ eps) as O^T = (eps^T)(L^T), 16x16x32 MFMA.
//          NEW expansion: dense (i,j) enumeration, t = i(i+1)/2+j (no sqrtf),
//          aligned 4B LDS stores with zero-fill fused (no separate zero pass).

typedef short bf16x8 __attribute__((ext_vector_type(8)));   // 8 bf16 in 4 VGPRs
typedef float f32x4 __attribute__((ext_vector_type(4)));

__device__ __forceinline__ unsigned short f2bf(float f) {
    union { float f; unsigned u; } u; u.f = f;
    unsigned r = u.u + 0x7FFFu + ((u.u >> 16) & 1u);   // RNE
    return (unsigned short)(r >> 16);
}

__device__ __forceinline__ int swz(int r) { return (r ^ (r >> 3)) & 7; }

// tri index -> (i,j)  (epilogue-only; once per fragment column)
__device__ __forceinline__ void tri_ij(int t, int& i, int& j) {
    i = (int)((sqrtf((float)(8 * t + 1)) - 1.0f) * 0.5f);
    if ((i + 1) * (i + 2) / 2 <= t) ++i;
    if (i * (i + 1) / 2 > t) --i;
    j = t - ((i * (i + 1)) >> 1);
}

__device__ __forceinline__ void gload16(const void* g, void* l) {
    __builtin_amdgcn_global_load_lds(
        (const __attribute__((address_space(1))) void*)g,
        (__attribute__((address_space(3))) void*)l, 16, 0, 0);
}

// ---------------- kernel 1: f32 -> bf16 convert (x and concat(w_mu, w_sigma)) ----
__global__ __launch_bounds__(256) void cvt_kernel(
    const float* __restrict__ x, const float* __restrict__ wmu,
    const float* __restrict__ wsig,
    unsigned short* __restrict__ Xb, unsigned short* __restrict__ Wb) {
    const int NX = (4096 * 512) / 4;
    const int NW = (2144 * 512) / 4;
    const int NMU = (64 * 512) / 4;
    int tot = NX + NW;
    for (int i = blockIdx.x * blockDim.x + threadIdx.x; i < tot;
         i += gridDim.x * blockDim.x) {
        float4 v; unsigned short* dst;
        if (i < NX) {
            v = ((const float4*)x)[i];
            dst = Xb + (size_t)i * 4;
        } else {
            int j = i - NX;
            if (j < NMU) v = ((const float4*)wmu)[j];
            else         v = ((const float4*)wsig)[j - NMU];
            dst = Wb + (size_t)j * 4;
        }
        ushort4 o;
        o.x = f2bf(v.x); o.y = f2bf(v.y); o.z = f2bf(v.z); o.w = f2bf(v.w);
        *(ushort4*)dst = o;
    }
}

// ---------------- kernel 2: GEMM + triangular-Sg epilogue ------------------------
// 128x128 tile, BK=64, 4 waves (2x2), LDS A[128][64]+B[128][64] bf16 = 32 KB.
// Stage: global_load_lds 16B/lane, linear LDS dest; source chunk pre-XOR'd so
// ds_read uses chunk ^ (row&7) -> conflict-free-ish reads (T2 via m173 pattern).
__global__ __launch_bounds__(256) void gemm_kernel(
    const unsigned short* __restrict__ Xb, const unsigned short* __restrict__ Wb,
    const float* __restrict__ bmu, const float* __restrict__ bsig,
    float* __restrict__ Mu, unsigned short* __restrict__ Sg) {
    __shared__ __align__(16) unsigned short smem[16384];   // A: [0,8192) B: [8192,16384)

    int flat = blockIdx.y * 17 + blockIdx.x;           // 0..543
    int virt = (flat & 7) * 68 + (flat >> 3);          // bijective XCD remap
    int vbx = virt % 17, vby = virt / 17;
    int r0 = vby * 128, c0 = vbx * 128;

    int tid = threadIdx.x;
    int w = tid >> 6, lane = tid & 63;
    int wr = w >> 1, wc = w & 1;
    int lr = lane & 15, kg = lane >> 4;

    // staging addresses: thread covers LDS 16B slot (row = i*32 + tid>>3, chunk = tid&7)
    int sr = tid >> 3;                 // 0..31 (row within 32-row stripe)
    int sc = tid & 7;                  // chunk 0..7
    int scx = sc ^ (sr & 7);           // inverse-swizzled source chunk
    const unsigned short* Ag = Xb + (size_t)(r0 + sr) * 512 + scx * 8;
    const unsigned short* Bg = Wb + (size_t)(c0 + sr) * 512 + scx * 8;
    unsigned short* As = smem + tid * 8;           // byte off = tid*16
    unsigned short* Bs = smem + 8192 + tid * 8;

    f32x4 acc[4][4];
    #pragma unroll
    for (int i = 0; i < 4; ++i)
        #pragma unroll
        for (int j = 0; j < 4; ++j) acc[i][j] = (f32x4){0.f, 0.f, 0.f, 0.f};

    for (int kt = 0; kt < 8; ++kt) {
        int k0 = kt * 64;
        #pragma unroll
        for (int i = 0; i < 4; ++i) {
            gload16(Ag + (size_t)i * 32 * 512 + k0, As + i * 2048);
            gload16(Bg + (size_t)i * 32 * 512 + k0, Bs + i * 2048);
        }
        __syncthreads();               // drains vmcnt -> staged tile visible
        #pragma unroll
        for (int h = 0; h < 2; ++h) {
            bf16x8 a[4], bv[4];
            #pragma unroll
            for (int i = 0; i < 4; ++i) {
                int row = wr * 64 + i * 16 + lr;
                int ch = ((h << 2) | kg) ^ (row & 7);
                a[i] = *(const bf16x8*)(smem + row * 64 + ch * 8);
            }
            #pragma unroll
            for (int j = 0; j < 4; ++j) {
                int row = wc * 64 + j * 16 + lr;
                int ch = ((h << 2) | kg) ^ (row & 7);
                bv[j] = *(const bf16x8*)(smem + 8192 + row * 64 + ch * 8);
            }
            #pragma unroll
            for (int i = 0; i < 4; ++i)
                #pragma unroll
                for (int j = 0; j < 4; ++j)
                    acc[i][j] = __builtin_amdgcn_mfma_f32_16x16x32_bf16(
                        a[i], bv[j], acc[i][j], 0, 0, 0);
        }
        __syncthreads();
    }

    // ---- epilogue: per j-fragment the 16 cols are entirely mu or entirely sigma
    int rbase = r0 + wr * 64 + (kg << 2);
    #pragma unroll
    for (int j = 0; j < 4; ++j) {
        int col = c0 + wc * 64 + j * 16 + lr;
        if (col < 64) {                        // mu head (wave-uniform branch)
            float bias = bmu[col];
            #pragma unroll
            for (int i = 0; i < 4; ++i)
                #pragma unroll
                for (int r = 0; r < 4; ++r)
                    Mu[(size_t)(rbase + i * 16 + r) * 64 + col] = acc[i][j][r] + bias;
        } else if (col < 2144) {               // sigma head -> triangular Sg
            int t = col - 64;
            float bias = bsig[t];
            int ti, tj; tri_ij(t, ti, tj);
            bool dg = (tj == ti);
            #pragma unroll
            for (int i = 0; i < 4; ++i) {
                #pragma unroll
                for (int r = 0; r < 4; ++r) {
                    float v = acc[i][j][r] + bias;
                    if (dg) v = (v > 15.f ? v : __logf(1.f + __expf(v))) + 1e-6f;
                    Sg[(size_t)(rbase + i * 16 + r) * 2080 + t] = f2bf(v);
                }
            }
        }
    }
}

// ---------------- kernel 3: out = sigmoid(mu + L @ eps) --------------------------
// 1 block = 1 b. 4 waves; wave w owns m-tiles {2w,2w+1} (w<3) or {6} (w==3).
__global__ __launch_bounds__(256) void sample_kernel(
    const float* __restrict__ Mu, const unsigned short* __restrict__ Sg,
    const float* __restrict__ eps, float* __restrict__ out) {
    __shared__ __align__(16) unsigned short Lh[64][64];      // dense L, swizzled, 8 KB
    __shared__ __align__(16) unsigned short Ep[4][32][64];   // per-wave eps^T, 16 KB

    int b = blockIdx.x;
    int tid = threadIdx.x;
    int w = tid >> 6;                          // wave-job id 0..3
    int lane = tid & 63;
    int M0 = w << 5;
    const float* er = eps + (size_t)b * 6400;

    // --- stage this wave's eps^T slice (transposed, chunk-swizzled, bf16) ---
    int ntask = (w < 3) ? 128 : 16;
    #pragma unroll
    for (int it = 0; it < 2; ++it) {
        int task = it * 64 + lane;
        if (task < ntask) {
            int mq = (w < 3) ? (task & 7) : 0;
            int kq = (w < 3) ? (task >> 3) : task;
            const float* p = er + kq * 400 + M0 + (mq << 2);
            float4 v0 = *(const float4*)(p);
            float4 v1 = *(const float4*)(p + 100);
            float4 v2 = *(const float4*)(p + 200);
            float4 v3 = *(const float4*)(p + 300);
            #pragma unroll
            for (int s = 0; s < 4; ++s) {
                int m = M0 + (mq << 2) + s;
                __hip_bfloat162 h0 = __float22bfloat162_rn(
                    make_float2(((const float*)&v0)[s], ((const float*)&v1)[s]));
                __hip_bfloat162 h1 = __float22bfloat162_rn(
                    make_float2(((const float*)&v2)[s], ((const float*)&v3)[s]));
                uint2 u; u.x = *(unsigned*)&h0; u.y = *(unsigned*)&h1;
                int chunk = (kq >> 1) ^ swz(m);
                *(uint2*)&Ep[w][m - M0][(chunk << 3) | ((kq & 1) << 2)] = u;
            }
        }
    }

    // --- expand Sg[b] -> dense swizzled L, DENSE enumeration ---
    // 2048 j-pairs over 64x64; t = i(i+1)/2 + j (no sqrtf); zero-fill fused;
    // aligned 4B LDS stores, conflict-free.
    const unsigned short* sgu = Sg + (size_t)b * 2080;
    #pragma unroll
    for (int k = 0; k < 8; ++k) {
        int idx = tid + (k << 8);              // 0..2047
        int i = idx >> 5;
        int j0 = (idx & 31) << 1;
        unsigned u = 0u;
        if (j0 <= i) {
            int t = ((i * (i + 1)) >> 1) + j0;
            u = sgu[t];
            if (j0 + 1 <= i) u |= ((unsigned)sgu[t + 1]) << 16;
        }
        *(unsigned*)&Lh[i][(((j0 >> 3) ^ swz(i)) << 3) | (j0 & 7)] = u;
    }

    // --- mu (global, independent of LDS) ---
    int lr = lane & 15, kg = lane >> 4;
    float muv[4];
    #pragma unroll
    for (int g = 0; g < 4; ++g) muv[g] = Mu[(b << 6) + g * 16 + lr];

    __syncthreads();

    // --- B-operand fragments: L rows i = g*16+lr from LDS ---
    bf16x8 Lf0[4], Lf1[4];
    #pragma unroll
    for (int g = 0; g < 4; ++g) {
        int i = g * 16 + lr;
        int si = swz(i);
        Lf0[g] = *(const bf16x8*)&Lh[i][(kg ^ si) << 3];
        Lf1[g] = *(const bf16x8*)&Lh[i][((kg + 4) ^ si) << 3];
    }

    // --- compute: for each owned m-tile, MFMA against all 4 concept groups ---
    int ntile = (w < 3) ? 2 : 1;
    for (int tt = 0; tt < ntile; ++tt) {
        int mt = (w < 3) ? (2 * w + tt) : 6;
        int m = (mt << 4) + lr;
        int lm = m - M0;
        int sm = swz(m);
        bf16x8 a0 = *(const bf16x8*)&Ep[w][lm][(kg ^ sm) << 3];
        bf16x8 a1 = *(const bf16x8*)&Ep[w][lm][((kg + 4) ^ sm) << 3];
        int m0 = (mt << 4) + (kg << 2);
        #pragma unroll
        for (int g = 0; g < 4; ++g) {
            f32x4 acc = {0.f, 0.f, 0.f, 0.f};
            acc = __builtin_amdgcn_mfma_f32_16x16x32_bf16(a0, Lf0[g], acc, 0, 0, 0);
            acc = __builtin_amdgcn_mfma_f32_16x16x32_bf16(a1, Lf1[g], acc, 0, 0, 0);
            if (m0 < 100) {
                float4 o;
                #pragma unroll
                for (int r = 0; r < 4; ++r) {
                    float z = muv[g] + acc[r];
                    ((float*)&o)[r] = __fdividef(1.f, 1.f + __expf(-z));
                }
                *(float4*)(out + ((size_t)b * 64 + g * 16 + lr) * 100 + m0) = o;
            }
        }
    }
}

extern "C" void kernel_launch(void* const* d_in, const int* in_sizes, int n_in,
                              void* d_out, int out_size, void* d_ws, size_t ws_size,
                              hipStream_t stream) {
    const float* x    = (const float*)d_in[0];
    const float* eps  = (const float*)d_in[1];
    const float* wmu  = (const float*)d_in[2];
    const float* bmu  = (const float*)d_in[3];
    const float* wsig = (const float*)d_in[4];
    const float* bsig = (const float*)d_in[5];
    float* out = (float*)d_out;

    char* ws = (char*)d_ws;
    unsigned short* Xb = (unsigned short*)ws;                      // 4,194,304 B
    unsigned short* Wb = (unsigned short*)(ws + 4194304);          // 2,195,456 B
    float*          Mu = (float*)(ws + 4194304 + 2195456);         // 1,048,576 B
    unsigned short* Sg = (unsigned short*)(ws + 4194304 + 2195456 + 1048576); // 17,039,360 B

    cvt_kernel<<<2048, 256, 0, stream>>>(x, wmu, wsig, Xb, Wb);
    // N-tail note: bx=16 stages B rows 2144..2175, which read past Wb into the
    // Mu region (allocated workspace, garbage values) — outputs there are
    // write-guarded, and MFMA columns are lane-independent, so this is safe.
    gemm_kernel<<<dim3(17, 32), 256, 0, stream>>>(Xb, Wb, bmu, bsig, Mu, Sg);
    sample_kernel<<<4096, 256, 0, stream>>>(Mu, Sg, eps, out);
}

// Round 2
// 79.844 us; speedup vs baseline: 1.5297x; 1.0732x over previous
//
#include <hip/hip_runtime.h>
#include <hip/hip_bf16.h>

// Problem: B=4096, F=512, C=64, MC=100, TRI=2080, N_all = 64+2080 = 2144
// Pipeline:
//  cvt:    x, [w_mu;w_sigma] -> bf16
//  gemm:   c_all = x @ W^T + bias. 128x128 tile, BK=64, LDS-staged via
//          global_load_lds(16B) with XOR-swizzled source; 17x32 grid, bijective
//          XCD remap. epilogue: cols<64 -> Mu f32; cols in [64,2144) -> Sg bf16
//          triangular (softplus+1e-6 on diagonal).
//  sample: out = sigmoid(mu + L @ eps) as O^T = (eps^T)(L^T), 16x16x32 MFMA.
//          NEW: 512 threads (8 waves), one m-tile per wave -> 32 waves/CU.
//          NEW: sigmoid results staged in swizzled LDS Ost[64][128] (union-
//          aliased over Lh+Ep) then stored as one contiguous 25.6 KB block
//          -> kills 1.25x write amplification + scattered 16B stores.

typedef short bf16x8 __attribute__((ext_vector_type(8)));   // 8 bf16 in 4 VGPRs
typedef float f32x4 __attribute__((ext_vector_type(4)));

__device__ __forceinline__ unsigned short f2bf(float f) {
    union { float f; unsigned u; } u; u.f = f;
    unsigned r = u.u + 0x7FFFu + ((u.u >> 16) & 1u);   // RNE
    return (unsigned short)(r >> 16);
}

__device__ __forceinline__ int swz(int r) { return (r ^ (r >> 3)) & 7; }

// tri index -> (i,j)  (gemm epilogue only; once per fragment column)
__device__ __forceinline__ void tri_ij(int t, int& i, int& j) {
    i = (int)((sqrtf((float)(8 * t + 1)) - 1.0f) * 0.5f);
    if ((i + 1) * (i + 2) / 2 <= t) ++i;
    if (i * (i + 1) / 2 > t) --i;
    j = t - ((i * (i + 1)) >> 1);
}

__device__ __forceinline__ void gload16(const void* g, void* l) {
    __builtin_amdgcn_global_load_lds(
        (const __attribute__((address_space(1))) void*)g,
        (__attribute__((address_space(3))) void*)l, 16, 0, 0);
}

// ---------------- kernel 1: f32 -> bf16 convert (x and concat(w_mu, w_sigma)) ----
__global__ __launch_bounds__(256) void cvt_kernel(
    const float* __restrict__ x, const float* __restrict__ wmu,
    const float* __restrict__ wsig,
    unsigned short* __restrict__ Xb, unsigned short* __restrict__ Wb) {
    const int NX = (4096 * 512) / 4;
    const int NW = (2144 * 512) / 4;
    const int NMU = (64 * 512) / 4;
    int tot = NX + NW;
    for (int i = blockIdx.x * blockDim.x + threadIdx.x; i < tot;
         i += gridDim.x * blockDim.x) {
        float4 v; unsigned short* dst;
        if (i < NX) {
            v = ((const float4*)x)[i];
            dst = Xb + (size_t)i * 4;
        } else {
            int j = i - NX;
            if (j < NMU) v = ((const float4*)wmu)[j];
            else         v = ((const float4*)wsig)[j - NMU];
            dst = Wb + (size_t)j * 4;
        }
        ushort4 o;
        o.x = f2bf(v.x); o.y = f2bf(v.y); o.z = f2bf(v.z); o.w = f2bf(v.w);
        *(ushort4*)dst = o;
    }
}

// ---------------- kernel 2: GEMM + triangular-Sg epilogue ------------------------
// 128x128 tile, BK=64, 4 waves (2x2), LDS A[128][64]+B[128][64] bf16 = 32 KB.
__global__ __launch_bounds__(256) void gemm_kernel(
    const unsigned short* __restrict__ Xb, const unsigned short* __restrict__ Wb,
    const float* __restrict__ bmu, const float* __restrict__ bsig,
    float* __restrict__ Mu, unsigned short* __restrict__ Sg) {
    __shared__ __align__(16) unsigned short smem[16384];   // A: [0,8192) B: [8192,16384)

    int flat = blockIdx.y * 17 + blockIdx.x;           // 0..543
    int virt = (flat & 7) * 68 + (flat >> 3);          // bijective XCD remap
    int vbx = virt % 17, vby = virt / 17;
    int r0 = vby * 128, c0 = vbx * 128;

    int tid = threadIdx.x;
    int w = tid >> 6, lane = tid & 63;
    int wr = w >> 1, wc = w & 1;
    int lr = lane & 15, kg = lane >> 4;

    int sr = tid >> 3;                 // 0..31 (row within 32-row stripe)
    int sc = tid & 7;                  // chunk 0..7
    int scx = sc ^ (sr & 7);           // inverse-swizzled source chunk
    const unsigned short* Ag = Xb + (size_t)(r0 + sr) * 512 + scx * 8;
    const unsigned short* Bg = Wb + (size_t)(c0 + sr) * 512 + scx * 8;
    unsigned short* As = smem + tid * 8;           // byte off = tid*16
    unsigned short* Bs = smem + 8192 + tid * 8;

    f32x4 acc[4][4];
    #pragma unroll
    for (int i = 0; i < 4; ++i)
        #pragma unroll
        for (int j = 0; j < 4; ++j) acc[i][j] = (f32x4){0.f, 0.f, 0.f, 0.f};

    for (int kt = 0; kt < 8; ++kt) {
        int k0 = kt * 64;
        #pragma unroll
        for (int i = 0; i < 4; ++i) {
            gload16(Ag + (size_t)i * 32 * 512 + k0, As + i * 2048);
            gload16(Bg + (size_t)i * 32 * 512 + k0, Bs + i * 2048);
        }
        __syncthreads();               // drains vmcnt -> staged tile visible
        #pragma unroll
        for (int h = 0; h < 2; ++h) {
            bf16x8 a[4], bv[4];
            #pragma unroll
            for (int i = 0; i < 4; ++i) {
                int row = wr * 64 + i * 16 + lr;
                int ch = ((h << 2) | kg) ^ (row & 7);
                a[i] = *(const bf16x8*)(smem + row * 64 + ch * 8);
            }
            #pragma unroll
            for (int j = 0; j < 4; ++j) {
                int row = wc * 64 + j * 16 + lr;
                int ch = ((h << 2) | kg) ^ (row & 7);
                bv[j] = *(const bf16x8*)(smem + 8192 + row * 64 + ch * 8);
            }
            #pragma unroll
            for (int i = 0; i < 4; ++i)
                #pragma unroll
                for (int j = 0; j < 4; ++j)
                    acc[i][j] = __builtin_amdgcn_mfma_f32_16x16x32_bf16(
                        a[i], bv[j], acc[i][j], 0, 0, 0);
        }
        __syncthreads();
    }

    int rbase = r0 + wr * 64 + (kg << 2);
    #pragma unroll
    for (int j = 0; j < 4; ++j) {
        int col = c0 + wc * 64 + j * 16 + lr;
        if (col < 64) {                        // mu head (wave-uniform branch)
            float bias = bmu[col];
            #pragma unroll
            for (int i = 0; i < 4; ++i)
                #pragma unroll
                for (int r = 0; r < 4; ++r)
                    Mu[(size_t)(rbase + i * 16 + r) * 64 + col] = acc[i][j][r] + bias;
        } else if (col < 2144) {               // sigma head -> triangular Sg
            int t = col - 64;
            float bias = bsig[t];
            int ti, tj; tri_ij(t, ti, tj);
            bool dg = (tj == ti);
            #pragma unroll
            for (int i = 0; i < 4; ++i) {
                #pragma unroll
                for (int r = 0; r < 4; ++r) {
                    float v = acc[i][j][r] + bias;
                    if (dg) v = (v > 15.f ? v : __logf(1.f + __expf(v))) + 1e-6f;
                    Sg[(size_t)(rbase + i * 16 + r) * 2080 + t] = f2bf(v);
                }
            }
        }
    }
}

// ---------------- kernel 3: out = sigmoid(mu + L @ eps) --------------------------
// 1 block = 1 b; 8 waves (512 thr), wave w<7 owns m-tile w. Output staged in
// swizzled LDS then stored as one contiguous 25.6 KB block.
__global__ __launch_bounds__(512, 8) void sample_kernel(
    const float* __restrict__ Mu, const unsigned short* __restrict__ Sg,
    const float* __restrict__ eps, float* __restrict__ out) {
    __shared__ __align__(16) union {
        struct {
            unsigned short Lh[64][64];     // dense L, swizzled, 8 KB
            unsigned short Ep[112][64];    // eps^T bf16, swizzled, 14 KB
        } s;
        float Ost[64][128];                // sigmoid output tile, swizzled, 32 KB
    } sm;

    int b = blockIdx.x;
    int tid = threadIdx.x;
    int w = tid >> 6;                          // wave 0..7
    int lane = tid & 63;
    const float* er = eps + (size_t)b * 6400;

    // --- stage eps^T (transposed, chunk-swizzled, bf16): 400 tasks = 25 mq x 16 kq
    if (tid < 400) {
        int mq = tid % 25, kq = tid / 25;      // m-quad 0..24, j-quad 0..15
        const float* p = er + kq * 400 + mq * 4;
        float4 v0 = *(const float4*)(p);
        float4 v1 = *(const float4*)(p + 100);
        float4 v2 = *(const float4*)(p + 200);
        float4 v3 = *(const float4*)(p + 300);
        #pragma unroll
        for (int s = 0; s < 4; ++s) {
            int m = (mq << 2) + s;
            __hip_bfloat162 h0 = __float22bfloat162_rn(
                make_float2(((const float*)&v0)[s], ((const float*)&v1)[s]));
            __hip_bfloat162 h1 = __float22bfloat162_rn(
                make_float2(((const float*)&v2)[s], ((const float*)&v3)[s]));
            uint2 u; u.x = *(unsigned*)&h0; u.y = *(unsigned*)&h1;
            int chunk = (kq >> 1) ^ swz(m);
            *(uint2*)&sm.s.Ep[m][(chunk << 3) | ((kq & 1) << 2)] = u;
        }
    }

    // --- expand Sg[b] -> dense swizzled L (dense enum, zero-fill fused) ---
    const unsigned short* sgu = Sg + (size_t)b * 2080;
    #pragma unroll
    for (int k = 0; k < 4; ++k) {
        int idx = tid + (k << 9);              // 0..2047
        int i = idx >> 5;
        int j0 = (idx & 31) << 1;
        unsigned u = 0u;
        if (j0 <= i) {
            int t = ((i * (i + 1)) >> 1) + j0;
            u = sgu[t];
            if (j0 + 1 <= i) u |= ((unsigned)sgu[t + 1]) << 16;
        }
        *(unsigned*)&sm.s.Lh[i][(((j0 >> 3) ^ swz(i)) << 3) | (j0 & 7)] = u;
    }

    // --- mu (global, independent of LDS) ---
    int lr = lane & 15, kg = lane >> 4;
    float muv[4];
    #pragma unroll
    for (int g = 0; g < 4; ++g) muv[g] = Mu[(b << 6) + g * 16 + lr];

    __syncthreads();                           // staging visible

    // --- fragment reads (must finish before Ost aliases the LDS) ---
    bf16x8 Lf0[4], Lf1[4], a0, a1;
    if (w < 7) {
        #pragma unroll
        for (int g = 0; g < 4; ++g) {
            int i = g * 16 + lr;
            int si = swz(i);
            Lf0[g] = *(const bf16x8*)&sm.s.Lh[i][(kg ^ si) << 3];
            Lf1[g] = *(const bf16x8*)&sm.s.Lh[i][((kg + 4) ^ si) << 3];
        }
        int m = (w << 4) + lr;
        int smz = swz(m);
        a0 = *(const bf16x8*)&sm.s.Ep[m][(kg ^ smz) << 3];
        a1 = *(const bf16x8*)&sm.s.Ep[m][((kg + 4) ^ smz) << 3];
    }

    __syncthreads();                           // all LDS reads done -> reuse as Ost

    // --- MFMA + sigmoid -> swizzled Ost ---
    if (w < 7) {
        int m0 = (w << 4) + (kg << 2);         // 0..108 step 4
        #pragma unroll
        for (int g = 0; g < 4; ++g) {
            f32x4 acc = {0.f, 0.f, 0.f, 0.f};
            acc = __builtin_amdgcn_mfma_f32_16x16x32_bf16(a0, Lf0[g], acc, 0, 0, 0);
            acc = __builtin_amdgcn_mfma_f32_16x16x32_bf16(a1, Lf1[g], acc, 0, 0, 0);
            if (m0 < 100) {
                int n = g * 16 + lr;
                float4 o;
                #pragma unroll
                for (int r = 0; r < 4; ++r) {
                    float z = muv[g] + acc[r];
                    ((float*)&o)[r] = __fdividef(1.f, 1.f + __expf(-z));
                }
                *(float4*)&sm.Ost[n][m0 ^ ((n & 7) << 2)] = o;
            }
        }
    }

    __syncthreads();                           // Ost complete

    // --- contiguous 25.6 KB block store (perfectly coalesced) ---
    #pragma unroll
    for (int k = 0; k < 4; ++k) {
        int f = tid + (k << 9);                // float4 index 0..2047
        if (f < 1600) {
            int row = f / 25;                  // 0..63
            int c4 = (f % 25) << 2;            // 0..96 step 4
            float4 v = *(const float4*)&sm.Ost[row][c4 ^ ((row & 7) << 2)];
            *(float4*)(out + ((size_t)b * 64 + row) * 100 + c4) = v;
        }
    }
}

extern "C" void kernel_launch(void* const* d_in, const int* in_sizes, int n_in,
                              void* d_out, int out_size, void* d_ws, size_t ws_size,
                              hipStream_t stream) {
    const float* x    = (const float*)d_in[0];
    const float* eps  = (const float*)d_in[1];
    const float* wmu  = (const float*)d_in[2];
    const float* bmu  = (const float*)d_in[3];
    const float* wsig = (const float*)d_in[4];
    const float* bsig = (const float*)d_in[5];
    float* out = (float*)d_out;

    char* ws = (char*)d_ws;
    unsigned short* Xb = (unsigned short*)ws;                      // 4,194,304 B
    unsigned short* Wb = (unsigned short*)(ws + 4194304);          // 2,195,456 B
    float*          Mu = (float*)(ws + 4194304 + 2195456);         // 1,048,576 B
    unsigned short* Sg = (unsigned short*)(ws + 4194304 + 2195456 + 1048576); // 17,039,360 B

    cvt_kernel<<<2048, 256, 0, stream>>>(x, wmu, wsig, Xb, Wb);
    // N-tail note: bx=16 stages B rows 2144..2175 (reads past Wb into Mu region,
    // allocated workspace) — outputs there are write-guarded; safe.
    gemm_kernel<<<dim3(17, 32), 256, 0, stream>>>(Xb, Wb, bmu, bsig, Mu, Sg);
    sample_kernel<<<4096, 512, 0, stream>>>(Mu, Sg, eps, out);
}

// Round 3
// 77.501 us; speedup vs baseline: 1.5760x; 1.0302x over previous
//
#include <hip/hip_runtime.h>
#include <hip/hip_bf16.h>

// Problem: B=4096, F=512, C=64, MC=100, TRI=2080, N_all = 64+2080 = 2144
// Pipeline:
//  cvt:    x, [w_mu;w_sigma] -> bf16
//  gemm:   c_all = x @ W^T + bias. 128x128 tile, BK=64, LDS-staged via
//          global_load_lds(16B) with XOR-swizzled source; 17x32 grid, bijective
//          XCD remap. epilogue: cols<64 -> Mu f32; cols in [64,2144) -> Sg bf16
//          triangular (softplus+1e-6 on diagonal).
//  sample: out = sigmoid(mu + L @ eps) as O^T = (eps^T)(L^T), 16x16x32 MFMA.
//          NEW: eps^T A-fragments loaded DIRECTLY from global per wave
//          (16 scalar f32, 64B-coalesced per 16-lane group, packed to bf16 in
//          regs) -> no Ep LDS staging, eps path off the barrier chain.
//          Only Sg->L expansion is barrier-gated. 2 barriers (was 3).
//          Lh 8KB + Ost 32KB separate (40KB; 4 blocks/CU = wave-slot cap).

typedef short bf16x8 __attribute__((ext_vector_type(8)));   // 8 bf16 in 4 VGPRs
typedef float f32x4 __attribute__((ext_vector_type(4)));

__device__ __forceinline__ unsigned short f2bf(float f) {
    union { float f; unsigned u; } u; u.f = f;
    unsigned r = u.u + 0x7FFFu + ((u.u >> 16) & 1u);   // RNE
    return (unsigned short)(r >> 16);
}

__device__ __forceinline__ int swz(int r) { return (r ^ (r >> 3)) & 7; }

// tri index -> (i,j)  (gemm epilogue only; once per fragment column)
__device__ __forceinline__ void tri_ij(int t, int& i, int& j) {
    i = (int)((sqrtf((float)(8 * t + 1)) - 1.0f) * 0.5f);
    if ((i + 1) * (i + 2) / 2 <= t) ++i;
    if (i * (i + 1) / 2 > t) --i;
    j = t - ((i * (i + 1)) >> 1);
}

__device__ __forceinline__ void gload16(const void* g, void* l) {
    __builtin_amdgcn_global_load_lds(
        (const __attribute__((address_space(1))) void*)g,
        (__attribute__((address_space(3))) void*)l, 16, 0, 0);
}

// ---------------- kernel 1: f32 -> bf16 convert (x and concat(w_mu, w_sigma)) ----
__global__ __launch_bounds__(256) void cvt_kernel(
    const float* __restrict__ x, const float* __restrict__ wmu,
    const float* __restrict__ wsig,
    unsigned short* __restrict__ Xb, unsigned short* __restrict__ Wb) {
    const int NX = (4096 * 512) / 4;
    const int NW = (2144 * 512) / 4;
    const int NMU = (64 * 512) / 4;
    int tot = NX + NW;
    for (int i = blockIdx.x * blockDim.x + threadIdx.x; i < tot;
         i += gridDim.x * blockDim.x) {
        float4 v; unsigned short* dst;
        if (i < NX) {
            v = ((const float4*)x)[i];
            dst = Xb + (size_t)i * 4;
        } else {
            int j = i - NX;
            if (j < NMU) v = ((const float4*)wmu)[j];
            else         v = ((const float4*)wsig)[j - NMU];
            dst = Wb + (size_t)j * 4;
        }
        ushort4 o;
        o.x = f2bf(v.x); o.y = f2bf(v.y); o.z = f2bf(v.z); o.w = f2bf(v.w);
        *(ushort4*)dst = o;
    }
}

// ---------------- kernel 2: GEMM + triangular-Sg epilogue ------------------------
// 128x128 tile, BK=64, 4 waves (2x2), LDS A[128][64]+B[128][64] bf16 = 32 KB.
__global__ __launch_bounds__(256) void gemm_kernel(
    const unsigned short* __restrict__ Xb, const unsigned short* __restrict__ Wb,
    const float* __restrict__ bmu, const float* __restrict__ bsig,
    float* __restrict__ Mu, unsigned short* __restrict__ Sg) {
    __shared__ __align__(16) unsigned short smem[16384];   // A: [0,8192) B: [8192,16384)

    int flat = blockIdx.y * 17 + blockIdx.x;           // 0..543
    int virt = (flat & 7) * 68 + (flat >> 3);          // bijective XCD remap
    int vbx = virt % 17, vby = virt / 17;
    int r0 = vby * 128, c0 = vbx * 128;

    int tid = threadIdx.x;
    int w = tid >> 6, lane = tid & 63;
    int wr = w >> 1, wc = w & 1;
    int lr = lane & 15, kg = lane >> 4;

    int sr = tid >> 3;                 // 0..31 (row within 32-row stripe)
    int sc = tid & 7;                  // chunk 0..7
    int scx = sc ^ (sr & 7);           // inverse-swizzled source chunk
    const unsigned short* Ag = Xb + (size_t)(r0 + sr) * 512 + scx * 8;
    const unsigned short* Bg = Wb + (size_t)(c0 + sr) * 512 + scx * 8;
    unsigned short* As = smem + tid * 8;           // byte off = tid*16
    unsigned short* Bs = smem + 8192 + tid * 8;

    f32x4 acc[4][4];
    #pragma unroll
    for (int i = 0; i < 4; ++i)
        #pragma unroll
        for (int j = 0; j < 4; ++j) acc[i][j] = (f32x4){0.f, 0.f, 0.f, 0.f};

    for (int kt = 0; kt < 8; ++kt) {
        int k0 = kt * 64;
        #pragma unroll
        for (int i = 0; i < 4; ++i) {
            gload16(Ag + (size_t)i * 32 * 512 + k0, As + i * 2048);
            gload16(Bg + (size_t)i * 32 * 512 + k0, Bs + i * 2048);
        }
        __syncthreads();               // drains vmcnt -> staged tile visible
        #pragma unroll
        for (int h = 0; h < 2; ++h) {
            bf16x8 a[4], bv[4];
            #pragma unroll
            for (int i = 0; i < 4; ++i) {
                int row = wr * 64 + i * 16 + lr;
                int ch = ((h << 2) | kg) ^ (row & 7);
                a[i] = *(const bf16x8*)(smem + row * 64 + ch * 8);
            }
            #pragma unroll
            for (int j = 0; j < 4; ++j) {
                int row = wc * 64 + j * 16 + lr;
                int ch = ((h << 2) | kg) ^ (row & 7);
                bv[j] = *(const bf16x8*)(smem + 8192 + row * 64 + ch * 8);
            }
            #pragma unroll
            for (int i = 0; i < 4; ++i)
                #pragma unroll
                for (int j = 0; j < 4; ++j)
                    acc[i][j] = __builtin_amdgcn_mfma_f32_16x16x32_bf16(
                        a[i], bv[j], acc[i][j], 0, 0, 0);
        }
        __syncthreads();
    }

    int rbase = r0 + wr * 64 + (kg << 2);
    #pragma unroll
    for (int j = 0; j < 4; ++j) {
        int col = c0 + wc * 64 + j * 16 + lr;
        if (col < 64) {                        // mu head (wave-uniform branch)
            float bias = bmu[col];
            #pragma unroll
            for (int i = 0; i < 4; ++i)
                #pragma unroll
                for (int r = 0; r < 4; ++r)
                    Mu[(size_t)(rbase + i * 16 + r) * 64 + col] = acc[i][j][r] + bias;
        } else if (col < 2144) {               // sigma head -> triangular Sg
            int t = col - 64;
            float bias = bsig[t];
            int ti, tj; tri_ij(t, ti, tj);
            bool dg = (tj == ti);
            #pragma unroll
            for (int i = 0; i < 4; ++i) {
                #pragma unroll
                for (int r = 0; r < 4; ++r) {
                    float v = acc[i][j][r] + bias;
                    if (dg) v = (v > 15.f ? v : __logf(1.f + __expf(v))) + 1e-6f;
                    Sg[(size_t)(rbase + i * 16 + r) * 2080 + t] = f2bf(v);
                }
            }
        }
    }
}

// ---------------- kernel 3: out = sigmoid(mu + L @ eps) --------------------------
// 1 block = 1 b; 8 waves (512 thr), wave w<7 owns m-tile w. eps^T A-fragments
// loaded directly from global (wave-local). L expanded to LDS (barrier-gated).
// Output staged in swizzled LDS Ost then stored as one contiguous block.
__global__ __launch_bounds__(512, 8) void sample_kernel(
    const float* __restrict__ Mu, const unsigned short* __restrict__ Sg,
    const float* __restrict__ eps, float* __restrict__ out) {
    __shared__ __align__(16) unsigned short Lh[64][64];   // dense L, swizzled, 8 KB
    __shared__ __align__(16) float Ost[64][128];          // output tile, swizzled, 32 KB

    int b = blockIdx.x;
    int tid = threadIdx.x;
    int w = tid >> 6;                          // wave 0..7
    int lane = tid & 63;
    int lr = lane & 15, kg = lane >> 4;
    const float* er = eps + (size_t)b * 6400;

    // --- eps^T A-fragments: 16 direct global f32 loads per lane (w<7) ---
    // lane needs eps^T[m][j] = er[j*100 + m], j = kg*8+s (a0) / 32+kg*8+s (a1).
    // 16-lane groups read 64B-contiguous segments. m>=100 lanes clamp to a
    // valid address; their output rows are never stored.
    float ef[16];
    int m = (w << 4) + lr;
    int ml = (m < 100) ? m : 96;
    if (w < 7) {
        #pragma unroll
        for (int s = 0; s < 8; ++s) {
            ef[s]     = er[(kg * 8 + s) * 100 + ml];
            ef[s + 8] = er[(32 + kg * 8 + s) * 100 + ml];
        }
    }

    // --- expand Sg[b] -> dense swizzled L (dense enum, zero-fill fused) ---
    const unsigned short* sgu = Sg + (size_t)b * 2080;
    #pragma unroll
    for (int k = 0; k < 4; ++k) {
        int idx = tid + (k << 9);              // 0..2047
        int i = idx >> 5;
        int j0 = (idx & 31) << 1;
        unsigned u = 0u;
        if (j0 <= i) {
            int t = ((i * (i + 1)) >> 1) + j0;
            u = sgu[t];
            if (j0 + 1 <= i) u |= ((unsigned)sgu[t + 1]) << 16;
        }
        *(unsigned*)&Lh[i][(((j0 >> 3) ^ swz(i)) << 3) | (j0 & 7)] = u;
    }

    // --- mu + pack eps frags to bf16 (reg-only, pre-barrier) ---
    float muv[4];
    bf16x8 a0, a1;
    if (w < 7) {
        #pragma unroll
        for (int g = 0; g < 4; ++g) muv[g] = Mu[(b << 6) + g * 16 + lr];
        #pragma unroll
        for (int s = 0; s < 4; ++s) {
            __hip_bfloat162 h0 = __float22bfloat162_rn(
                make_float2(ef[2 * s], ef[2 * s + 1]));
            __hip_bfloat162 h1 = __float22bfloat162_rn(
                make_float2(ef[8 + 2 * s], ef[8 + 2 * s + 1]));
            ((unsigned*)&a0)[s] = *(unsigned*)&h0;
            ((unsigned*)&a1)[s] = *(unsigned*)&h1;
        }
    }

    __syncthreads();                           // Lh visible

    // --- per-g: L frags from LDS, 2 MFMA, sigmoid -> swizzled Ost ---
    if (w < 7) {
        int m0 = (w << 4) + (kg << 2);         // 0..108 step 4
        #pragma unroll
        for (int g = 0; g < 4; ++g) {
            int i = g * 16 + lr;
            int si = swz(i);
            bf16x8 L0 = *(const bf16x8*)&Lh[i][(kg ^ si) << 3];
            bf16x8 L1 = *(const bf16x8*)&Lh[i][((kg + 4) ^ si) << 3];
            f32x4 acc = {0.f, 0.f, 0.f, 0.f};
            acc = __builtin_amdgcn_mfma_f32_16x16x32_bf16(a0, L0, acc, 0, 0, 0);
            acc = __builtin_amdgcn_mfma_f32_16x16x32_bf16(a1, L1, acc, 0, 0, 0);
            if (m0 < 100) {
                float4 o;
                #pragma unroll
                for (int r = 0; r < 4; ++r) {
                    float z = muv[g] + acc[r];
                    ((float*)&o)[r] = __fdividef(1.f, 1.f + __expf(-z));
                }
                *(float4*)&Ost[i][m0 ^ ((i & 7) << 2)] = o;
            }
        }
    }

    __syncthreads();                           // Ost complete

    // --- contiguous 25.6 KB block store (perfectly coalesced) ---
    #pragma unroll
    for (int k = 0; k < 4; ++k) {
        int f = tid + (k << 9);                // float4 index 0..2047
        if (f < 1600) {
            int row = f / 25;                  // 0..63
            int c4 = (f % 25) << 2;            // 0..96 step 4
            float4 v = *(const float4*)&Ost[row][c4 ^ ((row & 7) << 2)];
            *(float4*)(out + ((size_t)b * 64 + row) * 100 + c4) = v;
        }
    }
}

extern "C" void kernel_launch(void* const* d_in, const int* in_sizes, int n_in,
                              void* d_out, int out_size, void* d_ws, size_t ws_size,
                              hipStream_t stream) {
    const float* x    = (const float*)d_in[0];
    const float* eps  = (const float*)d_in[1];
    const float* wmu  = (const float*)d_in[2];
    const float* bmu  = (const float*)d_in[3];
    const float* wsig = (const float*)d_in[4];
    const float* bsig = (const float*)d_in[5];
    float* out = (float*)d_out;

    char* ws = (char*)d_ws;
    unsigned short* Xb = (unsigned short*)ws;                      // 4,194,304 B
    unsigned short* Wb = (unsigned short*)(ws + 4194304);          // 2,195,456 B
    float*          Mu = (float*)(ws + 4194304 + 2195456);         // 1,048,576 B
    unsigned short* Sg = (unsigned short*)(ws + 4194304 + 2195456 + 1048576); // 17,039,360 B

    cvt_kernel<<<2048, 256, 0, stream>>>(x, wmu, wsig, Xb, Wb);
    // N-tail note: bx=16 stages B rows 2144..2175 (reads past Wb into Mu region,
    // allocated workspace) — outputs there are write-guarded; safe.
    gemm_kernel<<<dim3(17, 32), 256, 0, stream>>>(Xb, Wb, bmu, bsig, Mu, Sg);
    sample_kernel<<<4096, 512, 0, stream>>>(Mu, Sg, eps, out);
}